// Round 1
// baseline (5467.497 us; speedup 1.0000x reference)
//
#include <hip/hip_runtime.h>
#include <math.h>

// Problem constants
#define H      8
#define SD     17      // OT+1 (s-part dim)
#define HD     240     // OS   (h-part dim)
#define OD     257     // OUT_DIM == IN_DIM
#define W2     2056    // H*OD
#define KTVSZ  66049   // OD*OD
#define NTOT   30000
#define CH     7500    // chunk rows
#define NCHUNK 4
#define SPLITS 4       // K-splits for ktv GEMM

// GEMM tile config
#define BM 64
#define BN 64
#define BK 16

__device__ __forceinline__ float phi_elu1(float x) {
    // elu(x)+1 : x>0 -> x+1 ; else exp(x)
    return x > 0.f ? x + 1.f : __expf(x);
}

// C[m,n] = sum_k A[m,k]*B[n,k]   (A: M x K, lda; B: N x K, ldb) -- both K-contiguous
__global__ void __launch_bounds__(256)
k_gemm_nt(const float* __restrict__ A, int lda,
          const float* __restrict__ B, int ldb,
          float* __restrict__ C, int ldc,
          int M, int N, int K)
{
    __shared__ float As[BK][BM + 4];
    __shared__ float Bs[BK][BN + 4];
    const int t  = threadIdx.x;
    const int m0 = blockIdx.x * BM;
    const int n0 = blockIdx.y * BN;
    const int tk = t & 15;      // k within tile (loads)
    const int tr = t >> 4;      // row/col group (loads)
    const int tx = t & 15;      // compute col group
    const int ty = t >> 4;      // compute row group
    float acc[4][4] = {};
    const int ksteps = (K + BK - 1) / BK;
    for (int ks = 0; ks < ksteps; ++ks) {
        const int kg = ks * BK + tk;
        const bool kv = kg < K;
#pragma unroll
        for (int i = 0; i < 4; ++i) {
            int m = m0 + tr + 16 * i;
            As[tk][tr + 16 * i] = (kv && m < M) ? A[(size_t)m * lda + kg] : 0.f;
        }
#pragma unroll
        for (int i = 0; i < 4; ++i) {
            int n = n0 + tr + 16 * i;
            Bs[tk][tr + 16 * i] = (kv && n < N) ? B[(size_t)n * ldb + kg] : 0.f;
        }
        __syncthreads();
#pragma unroll
        for (int k = 0; k < BK; ++k) {
            float a4[4], b4[4];
#pragma unroll
            for (int i = 0; i < 4; ++i) a4[i] = As[k][ty * 4 + i];
#pragma unroll
            for (int j = 0; j < 4; ++j) b4[j] = Bs[k][tx * 4 + j];
#pragma unroll
            for (int i = 0; i < 4; ++i)
#pragma unroll
                for (int j = 0; j < 4; ++j)
                    acc[i][j] = fmaf(a4[i], b4[j], acc[i][j]);
        }
        __syncthreads();
    }
#pragma unroll
    for (int i = 0; i < 4; ++i) {
        int m = m0 + ty * 4 + i;
        if (m >= M) continue;
#pragma unroll
        for (int j = 0; j < 4; ++j) {
            int n = n0 + tx * 4 + j;
            if (n < N) C[(size_t)m * ldc + n] = acc[i][j];
        }
    }
}

// ktv partials: Cp[split][h][m][n] += sum_{k in split} phiK[k, h*OD+m] * V[k, h*OD+n]
__global__ void __launch_bounds__(256)
k_gemm_tn_ktv(const float* __restrict__ phiK, const float* __restrict__ V,
              float* __restrict__ Cp, int rows)
{
    __shared__ float As[BK][BM + 4];
    __shared__ float Bs[BK][BN + 4];
    const int t     = threadIdx.x;
    const int h     = blockIdx.z & 7;
    const int split = blockIdx.z >> 3;
    const int m0 = blockIdx.x * BM;
    const int n0 = blockIdx.y * BN;
    const int kper = rows / SPLITS;
    const int kbeg = split * kper;
    const int kend = kbeg + kper;
    const int tc  = t & 63;   // column within tile (loads)
    const int tr4 = t >> 6;   // k row group (loads)
    const int tx = t & 15, ty = t >> 4;
    const float* Ab = phiK + h * OD;
    const float* Bb = V + h * OD;
    float acc[4][4] = {};
    const int ksteps = (kper + BK - 1) / BK;
    for (int ks = 0; ks < ksteps; ++ks) {
        const int kk0 = kbeg + ks * BK;
#pragma unroll
        for (int i = 0; i < 4; ++i) {
            int kk = kk0 + tr4 + 4 * i;
            bool kv = kk < kend;
            int m = m0 + tc;
            As[tr4 + 4 * i][tc] = (kv && m < OD) ? Ab[(size_t)kk * W2 + m] : 0.f;
            int n = n0 + tc;
            Bs[tr4 + 4 * i][tc] = (kv && n < OD) ? Bb[(size_t)kk * W2 + n] : 0.f;
        }
        __syncthreads();
#pragma unroll
        for (int k = 0; k < BK; ++k) {
            float a4[4], b4[4];
#pragma unroll
            for (int i = 0; i < 4; ++i) a4[i] = As[k][ty * 4 + i];
#pragma unroll
            for (int j = 0; j < 4; ++j) b4[j] = Bs[k][tx * 4 + j];
#pragma unroll
            for (int i = 0; i < 4; ++i)
#pragma unroll
                for (int j = 0; j < 4; ++j)
                    acc[i][j] = fmaf(a4[i], b4[j], acc[i][j]);
        }
        __syncthreads();
    }
    float* Cb = Cp + (size_t)(split * H + h) * KTVSZ;
#pragma unroll
    for (int i = 0; i < 4; ++i) {
        int m = m0 + ty * 4 + i;
        if (m >= OD) continue;
#pragma unroll
        for (int j = 0; j < 4; ++j) {
            int n = n0 + tx * 4 + j;
            if (n < OD) Cb[(size_t)m * OD + n] += acc[i][j];
        }
    }
}

__global__ void k_reduce_ktv(const float* __restrict__ Cp, float* __restrict__ ktv)
{
    int i = blockIdx.x * 256 + threadIdx.x;
    const int tot = H * KTVSZ;
    if (i < tot) {
        float s = 0.f;
        for (int sp = 0; sp < SPLITS; ++sp) s += Cp[(size_t)sp * tot + i];
        ktv[i] = s;
    }
}

// ksum[col] += partial column sums of phiK (rows x W2)
__global__ void k_ksum(const float* __restrict__ phiK, float* __restrict__ ksum, int rows)
{
    int col = blockIdx.x * 256 + threadIdx.x;
    if (col >= W2) return;
    int per = rows / gridDim.y;
    int r0  = blockIdx.y * per;
    float s = 0.f;
    for (int r = r0; r < r0 + per; ++r) s += phiK[(size_t)r * W2 + col];
    atomicAdd(&ksum[col], s);
}

// normalize s-part of Yk/Yv; phi on all of Yk; in place. One wave per (n,h).
__global__ void __launch_bounds__(256)
k_post_kv(float* __restrict__ Yk, float* __restrict__ Yv, int rows)
{
    int wid  = blockIdx.x * 4 + (threadIdx.x >> 6);
    int lane = threadIdx.x & 63;
    int n = wid >> 3, h = wid & 7;
    if (n >= rows) return;
    float* pk = Yk + (size_t)n * W2 + h * OD;
    float* pv = Yv + (size_t)n * W2 + h * OD;
    float kv0 = 0.f, vv0 = 0.f;
    if (lane < SD) { kv0 = pk[lane]; vv0 = pv[lane]; }
    float sk = kv0 * kv0, sv = vv0 * vv0;
#pragma unroll
    for (int off = 32; off > 0; off >>= 1) {
        sk += __shfl_down(sk, off);
        sv += __shfl_down(sv, off);
    }
    sk = __shfl(sk, 0); sv = __shfl(sv, 0);
    float invk = 1.f / (sqrtf(sk) + 1e-8f);
    float invv = 1.f / (sqrtf(sv) + 1e-8f);
    if (lane < SD) {
        pk[lane] = phi_elu1(kv0 * invk);
        pv[lane] = vv0 * invv;         // v h-part stays raw; only s-part rescaled
    }
    for (int o = SD + lane; o < OD; o += 64)
        pk[o] = phi_elu1(pk[o]);
}

// normalize s-part of Yq, phi all, compute den_s/den_h vs ksum. One wave per (n,h).
__global__ void __launch_bounds__(256)
k_post_q(float* __restrict__ Yq, const float* __restrict__ ksum,
         float* __restrict__ den_s, float* __restrict__ den_h, int rows)
{
    int wid  = blockIdx.x * 4 + (threadIdx.x >> 6);
    int lane = threadIdx.x & 63;
    int n = wid >> 3, h = wid & 7;
    if (n >= rows) return;
    float* pq = Yq + (size_t)n * W2 + h * OD;
    const float* ks = ksum + h * OD;
    float q0 = 0.f;
    if (lane < SD) q0 = pq[lane];
    float sq = q0 * q0;
#pragma unroll
    for (int off = 32; off > 0; off >>= 1) sq += __shfl_down(sq, off);
    sq = __shfl(sq, 0);
    float invq = 1.f / (sqrtf(sq) + 1e-8f);
    float ds = 0.f, dh = 0.f;
    if (lane < SD) {
        float p = phi_elu1(q0 * invq);
        pq[lane] = p;
        ds = p * ks[lane];
    }
    for (int o = SD + lane; o < OD; o += 64) {
        float p = phi_elu1(pq[o]);
        pq[o] = p;
        dh += p * ks[o];
    }
#pragma unroll
    for (int off = 32; off > 0; off >>= 1) {
        ds += __shfl_down(ds, off);
        dh += __shfl_down(dh, off);
    }
    if (lane == 0) { den_s[n * H + h] = ds; den_h[n * H + h] = dh; }
}

// num[m, h*D+n] = (sum_k phiQ[m, h*OD+P+k] * ktv[h, P+k, P+n]) / (den[m*H+h]+eps)
__global__ void __launch_bounds__(256)
k_gemm_nn_att(const float* __restrict__ phiQ, const float* __restrict__ ktv,
              const float* __restrict__ den, float* __restrict__ Cout,
              int M, int D, int P, float eps)
{
    __shared__ float As[BK][BM + 4];
    __shared__ float Bs[BK][BN + 4];
    const int t = threadIdx.x;
    const int h = blockIdx.z;
    const int m0 = blockIdx.x * BM, n0 = blockIdx.y * BN;
    const float* A = phiQ + h * OD + P;                       // lda = W2
    const float* B = ktv + (size_t)h * KTVSZ + P * OD + P;    // ldb = OD
    const int ldc = H * D;
    const int tka = t & 15, tma = t >> 4;   // A loads
    const int tnb = t & 63, tkb = t >> 6;   // B loads
    const int tx = t & 15, ty = t >> 4;
    float acc[4][4] = {};
    const int ksteps = (D + BK - 1) / BK;
    for (int ks = 0; ks < ksteps; ++ks) {
        const int k0 = ks * BK;
#pragma unroll
        for (int i = 0; i < 4; ++i) {
            int m = m0 + tma + 16 * i;
            int k = k0 + tka;
            As[tka][tma + 16 * i] = (m < M && k < D) ? A[(size_t)m * W2 + k] : 0.f;
        }
#pragma unroll
        for (int i = 0; i < 4; ++i) {
            int k = k0 + tkb + 4 * i;
            int n = n0 + tnb;
            Bs[tkb + 4 * i][tnb] = (k < D && n < D) ? B[(size_t)k * OD + n] : 0.f;
        }
        __syncthreads();
#pragma unroll
        for (int k = 0; k < BK; ++k) {
            float a4[4], b4[4];
#pragma unroll
            for (int i = 0; i < 4; ++i) a4[i] = As[k][ty * 4 + i];
#pragma unroll
            for (int j = 0; j < 4; ++j) b4[j] = Bs[k][tx * 4 + j];
#pragma unroll
            for (int i = 0; i < 4; ++i)
#pragma unroll
                for (int j = 0; j < 4; ++j)
                    acc[i][j] = fmaf(a4[i], b4[j], acc[i][j]);
        }
        __syncthreads();
    }
#pragma unroll
    for (int i = 0; i < 4; ++i) {
        int m = m0 + ty * 4 + i;
        if (m >= M) continue;
        float s = 1.f / (den[m * H + h] + eps);
#pragma unroll
        for (int j = 0; j < 4; ++j) {
            int n = n0 + tx * 4 + j;
            if (n < D) Cout[(size_t)m * ldc + h * D + n] = acc[i][j] * s;
        }
    }
}

// final epilogue: norms, masks, bt, assemble out row. One wave per n.
__global__ void __launch_bounds__(256)
k_finalize(const float* __restrict__ s_out, const float* __restrict__ h_out,
           float* __restrict__ outp, int rows)
{
    int n    = blockIdx.x * 4 + (threadIdx.x >> 6);
    int lane = threadIdx.x & 63;
    if (n >= rows) return;
    const float* sp = s_out + (size_t)n * SD;
    const float* hp = h_out + (size_t)n * HD;
    float* op = outp + (size_t)n * OD;
    float sv = (lane < SD) ? sp[lane] : 0.f;
    float ssq = sv * sv;
    float hv[4];
    float hsq = 0.f;
#pragma unroll
    for (int i = 0; i < 4; ++i) {
        int o = lane + 64 * i;
        hv[i] = (o < HD) ? hp[o] : 0.f;
        hsq += hv[i] * hv[i];
    }
#pragma unroll
    for (int off = 32; off > 0; off >>= 1) {
        ssq += __shfl_down(ssq, off);
        hsq += __shfl_down(hsq, off);
    }
    ssq = __shfl(ssq, 0); hsq = __shfl(hsq, 0);
    float an_raw = sqrtf(ssq);
    float bn_raw = sqrtf(hsq);
    float an = an_raw + 1e-8f;
    float bn = bn_raw + 1e-8f;
    bool ma = an > 1e6f;
    bool mb = bn > 1e6f;
    float an_c = fminf(an, 1e6f);
    float bn_c = fminf(bn, 1e6f);
    // att_s = a_ / max(||a_||, 1e-12), a_ = ma ? a/an_c : a
    float na = ma ? (an_raw / an_c) : an_raw;
    na = fmaxf(na, 1e-12f);
    float inv_s = (ma ? (1.f / an_c) : 1.f) / na;
    // b_ = l2norm(b/bn_c)*1e6 ; b2 = mb ? b_ : b
    float bt = sqrtf(bn_c * bn_c + 1.0f);
    float nb = fmaxf(bn_raw / bn_c, 1e-12f);
    float scale_b = 1e6f / (bn_c * nb);
    if (lane < SD) op[lane] = bt * (sv * inv_s);
#pragma unroll
    for (int i = 0; i < 4; ++i) {
        int o = lane + 64 * i;
        if (o < HD) op[SD + o] = mb ? hv[i] * scale_b : hv[i];
    }
}

extern "C" void kernel_launch(void* const* d_in, const int* in_sizes, int n_in,
                              void* d_out, int out_size, void* d_ws, size_t ws_size,
                              hipStream_t stream)
{
    const float* query  = (const float*)d_in[0];
    const float* source = (const float*)d_in[1];
    const float* Wq     = (const float*)d_in[2];
    const float* Wk     = (const float*)d_in[3];
    const float* Wv     = (const float*)d_in[4];
    const float* Ws     = (const float*)d_in[5];
    const float* Wh     = (const float*)d_in[6];
    float* out = (float*)d_out;
    float* ws  = (float*)d_ws;

    // workspace layout (floats); total ~35.6M floats = ~142 MB
    float* wsA   = ws;                                  // CH*W2
    float* wsB   = wsA  + (size_t)CH * W2;              // CH*W2 (V, later num_h/num_s)
    float* ktvp  = wsB  + (size_t)CH * W2;              // SPLITS*H*KTVSZ
    float* ktv   = ktvp + (size_t)SPLITS * H * KTVSZ;   // H*KTVSZ
    float* ksum  = ktv  + (size_t)H * KTVSZ;            // W2
    float* den_s = ksum + W2;                           // CH*H
    float* den_h = den_s + (size_t)CH * H;              // CH*H
    float* h_out = den_h + (size_t)CH * H;              // CH*HD
    float* s_out = h_out + (size_t)CH * HD;             // CH*SD
    float* num_h = wsB;                                 // CH*H*HD (overlays V)
    float* num_s = wsB + (size_t)CH * H * HD;           // CH*H*SD

    hipMemsetAsync(ktvp, 0, (size_t)SPLITS * H * KTVSZ * sizeof(float), stream);
    hipMemsetAsync(ksum, 0, (size_t)W2 * sizeof(float), stream);

    const dim3 gBig((CH + BM - 1) / BM, (W2 + BN - 1) / BN);      // 118 x 33
    const dim3 gKtv((OD + BM - 1) / BM, (OD + BN - 1) / BN, H * SPLITS); // 5x5x32

    // ---- source side: build ktv + ksum ----
    for (int c = 0; c < NCHUNK; ++c) {
        const float* src = source + (size_t)c * CH * OD;
        k_gemm_nt<<<gBig, 256, 0, stream>>>(src, OD, Wk, OD, wsA, W2, CH, W2, OD);
        k_gemm_nt<<<gBig, 256, 0, stream>>>(src, OD, Wv, OD, wsB, W2, CH, W2, OD);
        k_post_kv<<<CH * H / 4, 256, 0, stream>>>(wsA, wsB, CH);
        k_gemm_tn_ktv<<<gKtv, 256, 0, stream>>>(wsA, wsB, ktvp, CH);
        k_ksum<<<dim3((W2 + 255) / 256, 30), 256, 0, stream>>>(wsA, ksum, CH);
    }
    k_reduce_ktv<<<(H * KTVSZ + 255) / 256, 256, 0, stream>>>(ktvp, ktv);

    // ---- query side ----
    for (int c = 0; c < NCHUNK; ++c) {
        const float* qsrc = query + (size_t)c * CH * OD;
        float* orow = out + (size_t)c * CH * OD;
        k_gemm_nt<<<gBig, 256, 0, stream>>>(qsrc, OD, Wq, OD, wsA, W2, CH, W2, OD);
        k_post_q<<<CH * H / 4, 256, 0, stream>>>(wsA, ksum, den_s, den_h, CH);
        k_gemm_nn_att<<<dim3((CH + BM - 1) / BM, 1, H), 256, 0, stream>>>(
            wsA, ktv, den_s, num_s, CH, SD, 0, 1e-6f);
        k_gemm_nn_att<<<dim3((CH + BM - 1) / BM, (HD + BN - 1) / BN, H), 256, 0, stream>>>(
            wsA, ktv, den_h, num_h, CH, HD, SD, 1e-8f);
        k_gemm_nt<<<dim3((CH + BM - 1) / BM, 1), 256, 0, stream>>>(
            num_s, H * SD, Ws, H * SD, s_out, SD, CH, SD, H * SD);
        k_gemm_nt<<<dim3((CH + BM - 1) / BM, (HD + BN - 1) / BN), 256, 0, stream>>>(
            num_h, H * HD, Wh, H * HD, h_out, HD, CH, HD, H * HD);
        k_finalize<<<CH / 4, 256, 0, stream>>>(s_out, h_out, orow, CH);
    }
}

// Round 3
// 2522.524 us; speedup vs baseline: 2.1675x; 2.1675x over previous
//
#include <hip/hip_runtime.h>
#include <math.h>

typedef __bf16 bf16_t;
typedef __bf16 bf16x8 __attribute__((ext_vector_type(8)));
typedef float f32x4 __attribute__((ext_vector_type(4)));

#define H    8
#define SD   17
#define HD   240
#define OD   257
#define W2   2056
#define KIN  257
#define KP   288     // padded K for qkv gemms (mult of 32)
#define NTOT 30000

// MFMA NT GEMM tile config
#define BM 128
#define BN 128
#define BK 32
#define LDSP 40     // LDS row stride in bf16 (32 + 8 pad)

__device__ __forceinline__ float phi_elu1(float x) {
    return x > 0.f ? x + 1.f : __expf(x);
}

struct GemmP {
    const bf16_t* A; long lda; long aHead;
    const bf16_t* B; long ldb; long bHead;
    float* Cf; bf16_t* Cb; long ldc; long cHead;
    const float* rs; int rsStride; int rsHead; float eps;
    int M, N, K;
    int nSplit;     // gridDim.z = H_eff * nSplit ; h = z/nSplit, split = z%nSplit
    int atomicC;
};

// C[m,n] = sum_k A[m,k] * B[n,k]  (both operands k-contiguous bf16, f32 acc)
__global__ void __launch_bounds__(256)
k_mfma_nt(GemmP p)
{
    __shared__ bf16_t As[BM * LDSP];
    __shared__ bf16_t Bs[BN * LDSP];
    const int t  = threadIdx.x;
    const int z  = blockIdx.z;
    const int h  = z / p.nSplit;
    const int sp = z % p.nSplit;
    const int kWin = p.K / p.nSplit;
    const int k0   = sp * kWin;
    const int m0 = blockIdx.x * BM;
    const int n0 = blockIdx.y * BN;
    const bf16_t* A = p.A + (long)h * p.aHead;
    const bf16_t* B = p.B + (long)h * p.bHead;

    const int lr = t >> 2;     // 0..63 staging row
    const int lc = t & 3;      // k-chunk (x8)
    const int wid  = t >> 6;
    const int lane = t & 63;
    const int wm = (wid >> 1) * 64;
    const int wn = (wid & 1) * 64;
    const int fr = lane & 15;
    const int fq = lane >> 4;

    f32x4 acc[4][4] = {};

    for (int kb = k0; kb < k0 + kWin; kb += BK) {
#pragma unroll
        for (int it = 0; it < 2; ++it) {
            const int r  = lr + it * 64;
            const int gk = kb + lc * 8;
            const bool kok = gk < p.K;
            const int gm = m0 + r;
            bf16x8 va = {};
            if (kok && gm < p.M) va = *(const bf16x8*)(A + (long)gm * p.lda + gk);
            *(bf16x8*)(As + r * LDSP + lc * 8) = va;
            const int gn = n0 + r;
            bf16x8 vb = {};
            if (kok && gn < p.N) vb = *(const bf16x8*)(B + (long)gn * p.ldb + gk);
            *(bf16x8*)(Bs + r * LDSP + lc * 8) = vb;
        }
        __syncthreads();
        bf16x8 af[4], bfr[4];
#pragma unroll
        for (int i = 0; i < 4; ++i)
            af[i] = *(const bf16x8*)(As + (wm + i * 16 + fr) * LDSP + fq * 8);
#pragma unroll
        for (int j = 0; j < 4; ++j)
            bfr[j] = *(const bf16x8*)(Bs + (wn + j * 16 + fr) * LDSP + fq * 8);
#pragma unroll
        for (int i = 0; i < 4; ++i)
#pragma unroll
            for (int j = 0; j < 4; ++j)
                acc[i][j] = __builtin_amdgcn_mfma_f32_16x16x32_bf16(af[i], bfr[j], acc[i][j], 0, 0, 0);
        __syncthreads();
    }

    float*  Cf = p.Cf ? p.Cf + (long)h * p.cHead : (float*)0;
    bf16_t* Cb = p.Cb ? p.Cb + (long)h * p.cHead : (bf16_t*)0;
    const float* rs = p.rs ? p.rs + (long)h * p.rsHead : (const float*)0;
#pragma unroll
    for (int i = 0; i < 4; ++i) {
#pragma unroll
        for (int r = 0; r < 4; ++r) {
            const int m = m0 + wm + i * 16 + fq * 4 + r;
            if (m >= p.M) continue;
            float sc = 1.f;
            if (rs) sc = 1.f / (rs[(long)m * p.rsStride] + p.eps);
#pragma unroll
            for (int j = 0; j < 4; ++j) {
                const int n = n0 + wn + j * 16 + fr;
                if (n >= p.N) continue;
                const float v = acc[i][j][r] * sc;
                const long idx = (long)m * p.ldc + n;
                if (p.atomicC)      atomicAdd(&Cf[idx], v);
                else if (Cf)        Cf[idx] = v;
                else                Cb[idx] = (bf16_t)v;
            }
        }
    }
}

// pad-cast f32 [rows][kin] -> bf16 [rows][kout], zeros for k>=kin
__global__ void k_cast_pad(const float* __restrict__ in, bf16_t* __restrict__ out,
                           long rows, int kin, int kout)
{
    long i = (long)blockIdx.x * 256 + threadIdx.x;
    if (i >= rows * kout) return;
    long r = i / kout; int k = (int)(i - r * kout);
    out[i] = (k < kin) ? (bf16_t)in[r * kin + k] : (bf16_t)0.f;
}

// Ws [17][136] -> Wsb [17][256] head-split padded
__global__ void k_cast_ws(const float* __restrict__ ws, bf16_t* __restrict__ out)
{
    int o = blockIdx.x; int t = threadIdx.x;
    int h = t >> 5, j = t & 31;
    out[o * 256 + t] = (j < SD) ? (bf16_t)ws[o * (H * SD) + h * SD + j] : (bf16_t)0.f;
}

// f32 -> bf16 elementwise
__global__ void k_castf(const float* __restrict__ in, bf16_t* __restrict__ out, long n)
{
    long i = (long)blockIdx.x * 256 + threadIdx.x;
    if (i < n) out[i] = (bf16_t)in[i];
}

// transpose bf16 X[R][W] -> T[W][CHP], zero-fill rows R..CHP. Tile 128r x 64c.
__global__ void __launch_bounds__(256)
k_transpose(const bf16_t* __restrict__ X, bf16_t* __restrict__ T,
            int R, int W, int CHP_)
{
    const int t = threadIdx.x;
    const int c = t & 63;
    const int rchunk = t >> 6;           // 0..3
    const int r0 = blockIdx.x * 128;
    const int c0 = blockIdx.y * 64;
    const int gc = c0 + c;
    bf16x8 w[4];
#pragma unroll
    for (int j = 0; j < 32; ++j) {
        const int gr = r0 + rchunk * 32 + j;
        float v = 0.f;
        if (gr < R) v = (float)X[(long)gr * W + gc];
        w[j >> 3][j & 7] = (bf16_t)v;
    }
    bf16_t* dst = T + (long)gc * CHP_ + r0 + rchunk * 32;
#pragma unroll
    for (int q = 0; q < 4; ++q)
        *(bf16x8*)(dst + q * 8) = w[q];
}

// post for k/v: s-part l2norm (+phi for k), h-part (+phi for k), write split bf16
__global__ void __launch_bounds__(256)
k_post(const float* __restrict__ Y, bf16_t* __restrict__ outS, bf16_t* __restrict__ outH,
       int rows, int applyPhi)
{
    const int wid  = blockIdx.x * 4 + (threadIdx.x >> 6);
    const int lane = threadIdx.x & 63;
    const int n = wid >> 3, h = wid & 7;
    if (n >= rows) return;
    const float* y = Y + (long)n * W2 + h * OD;
    float v0 = (lane < SD) ? y[lane] : 0.f;
    float s = v0 * v0;
#pragma unroll
    for (int off = 32; off > 0; off >>= 1) s += __shfl_down(s, off);
    s = __shfl(s, 0);
    const float inv = 1.f / (sqrtf(s) + 1e-8f);
    if (lane < 32) {
        float val = (lane < SD) ? v0 * inv : 0.f;
        if (applyPhi && lane < SD) val = phi_elu1(val);
        outS[(long)n * 256 + h * 32 + lane] = (bf16_t)val;
    }
    for (int o = SD + lane; o < OD; o += 64) {
        float val = y[o];
        if (applyPhi) val = phi_elu1(val);
        outH[(long)n * 1920 + h * HD + (o - SD)] = (bf16_t)val;
    }
}

// post for q: like k_post(applyPhi=1) + den_s/den_h from bf16-rounded phi and ksum
__global__ void __launch_bounds__(256)
k_post_q(const float* __restrict__ Y, const float* __restrict__ ksum_s,
         const float* __restrict__ ksum_h, bf16_t* __restrict__ outS,
         bf16_t* __restrict__ outH, float* __restrict__ den_s, float* __restrict__ den_h,
         int rows)
{
    const int wid  = blockIdx.x * 4 + (threadIdx.x >> 6);
    const int lane = threadIdx.x & 63;
    const int n = wid >> 3, h = wid & 7;
    if (n >= rows) return;
    const float* y = Y + (long)n * W2 + h * OD;
    float v0 = (lane < SD) ? y[lane] : 0.f;
    float s = v0 * v0;
#pragma unroll
    for (int off = 32; off > 0; off >>= 1) s += __shfl_down(s, off);
    s = __shfl(s, 0);
    const float inv = 1.f / (sqrtf(s) + 1e-8f);
    float ds = 0.f, dh = 0.f;
    if (lane < 32) {
        float val = 0.f;
        if (lane < SD) {
            bf16_t b = (bf16_t)phi_elu1(v0 * inv);
            outS[(long)n * 256 + h * 32 + lane] = b;
            ds = (float)b * ksum_s[h * 32 + lane];
        } else {
            outS[(long)n * 256 + h * 32 + lane] = (bf16_t)val;
        }
    }
    for (int o = SD + lane; o < OD; o += 64) {
        bf16_t b = (bf16_t)phi_elu1(y[o]);
        outH[(long)n * 1920 + h * HD + (o - SD)] = b;
        dh += (float)b * ksum_h[h * HD + (o - SD)];
    }
#pragma unroll
    for (int off = 32; off > 0; off >>= 1) {
        ds += __shfl_down(ds, off);
        dh += __shfl_down(dh, off);
    }
    if (lane == 0) { den_s[n * H + h] = ds; den_h[n * H + h] = dh; }
}

// column sums of bf16 [rows][W] -> f32 out[W] (atomic across row splits)
__global__ void k_colsum(const bf16_t* __restrict__ X, float* __restrict__ out,
                         int rows, int W)
{
    int col = blockIdx.x * 256 + threadIdx.x;
    if (col >= W) return;
    int per = (rows + gridDim.y - 1) / gridDim.y;
    int r0 = blockIdx.y * per;
    int r1 = r0 + per; if (r1 > rows) r1 = rows;
    float s = 0.f;
    for (int r = r0; r < r1; ++r) s += (float)X[(long)r * W + col];
    atomicAdd(&out[col], s);
}

// final epilogue, one wave per row n (identical math to the passing round-1 kernel)
__global__ void __launch_bounds__(256)
k_finalize(const float* __restrict__ s_out, const float* __restrict__ h_out,
           float* __restrict__ outp, int rows)
{
    int n    = blockIdx.x * 4 + (threadIdx.x >> 6);
    int lane = threadIdx.x & 63;
    if (n >= rows) return;
    const float* sp = s_out + (long)n * SD;
    const float* hp = h_out + (long)n * HD;
    float* op = outp + (long)n * OD;
    float sv = (lane < SD) ? sp[lane] : 0.f;
    float ssq = sv * sv;
    float hv[4];
    float hsq = 0.f;
#pragma unroll
    for (int i = 0; i < 4; ++i) {
        int o = lane + 64 * i;
        hv[i] = (o < HD) ? hp[o] : 0.f;
        hsq += hv[i] * hv[i];
    }
#pragma unroll
    for (int off = 32; off > 0; off >>= 1) {
        ssq += __shfl_down(ssq, off);
        hsq += __shfl_down(hsq, off);
    }
    ssq = __shfl(ssq, 0); hsq = __shfl(hsq, 0);
    float an_raw = sqrtf(ssq);
    float bn_raw = sqrtf(hsq);
    float an = an_raw + 1e-8f;
    float bn = bn_raw + 1e-8f;
    bool ma = an > 1e6f;
    bool mb = bn > 1e6f;
    float an_c = fminf(an, 1e6f);
    float bn_c = fminf(bn, 1e6f);
    float na = ma ? (an_raw / an_c) : an_raw;
    na = fmaxf(na, 1e-12f);
    float inv_s = (ma ? (1.f / an_c) : 1.f) / na;
    float bt = sqrtf(bn_c * bn_c + 1.0f);
    float nb = fmaxf(bn_raw / bn_c, 1e-12f);
    float scale_b = 1e6f / (bn_c * nb);
    if (lane < SD) op[lane] = bt * (sv * inv_s);
#pragma unroll
    for (int i = 0; i < 4; ++i) {
        int o = lane + 64 * i;
        if (o < HD) op[SD + o] = mb ? hv[i] * scale_b : hv[i];
    }
}

static inline long alup(long b) { return (b + 255) & ~255L; }

static long layout_bytes(long CH, long CHP)
{
    long tot = 0;
    tot += 3 * alup(2056L * KP * 2);            // Wq/Wk/Wv bf16
    tot += alup(17L * 256 * 2);                 // Wsb
    tot += alup(240L * 1920 * 2);               // Whb
    tot += alup(CH * KP * 2);                   // xcb
    tot += alup(CH * W2 * 4);                   // Y f32
    tot += 2 * (alup(CH * 256 * 2) + alup(CH * 1920 * 2));  // phiS/phiH + vS/vH
    tot += 2 * alup(256L * CHP * 2);            // TsK, TsV
    tot += 2 * alup(1920L * CHP * 2);           // ThK, ThV
    tot += alup(8L * 32 * 32 * 4) + alup(8L * 240 * 256 * 4);  // ktv f32
    tot += alup(8L * 32 * 32 * 2) + alup(8L * 240 * 256 * 2);  // ktv bf16
    tot += alup(256L * 4) + alup(1920L * 4);    // ksums
    return tot;
}

extern "C" void kernel_launch(void* const* d_in, const int* in_sizes, int n_in,
                              void* d_out, int out_size, void* d_ws, size_t ws_size,
                              hipStream_t stream)
{
    const float* query  = (const float*)d_in[0];
    const float* source = (const float*)d_in[1];
    const float* Wq     = (const float*)d_in[2];
    const float* Wk     = (const float*)d_in[3];
    const float* Wv     = (const float*)d_in[4];
    const float* Ws     = (const float*)d_in[5];
    const float* Wh     = (const float*)d_in[6];
    float* out = (float*)d_out;

    // pick chunk size that fits workspace
    const long cands[4] = {7500, 5000, 3750, 2500};
    long CH = 2500;
    for (int i = 0; i < 4; ++i) {
        long chp = (cands[i] + 255) & ~255L;
        if (layout_bytes(cands[i], chp) <= (long)ws_size) { CH = cands[i]; break; }
    }
    const long CHP = (CH + 255) & ~255L;
    const int NCHUNK = (int)(NTOT / CH);

    // allocate
    char* p = (char*)d_ws;
    auto alloc = [&](long b) { char* r = p; p += alup(b); return r; };
    bf16_t* Wqb  = (bf16_t*)alloc(2056L * KP * 2);
    bf16_t* Wkb  = (bf16_t*)alloc(2056L * KP * 2);
    bf16_t* Wvb  = (bf16_t*)alloc(2056L * KP * 2);
    bf16_t* Wsb  = (bf16_t*)alloc(17L * 256 * 2);
    bf16_t* Whb  = (bf16_t*)alloc(240L * 1920 * 2);
    bf16_t* xcb  = (bf16_t*)alloc(CH * KP * 2);
    float*  Y    = (float*) alloc(CH * W2 * 4);
    bf16_t* phiS = (bf16_t*)alloc(CH * 256 * 2);
    bf16_t* phiH = (bf16_t*)alloc(CH * 1920 * 2);
    bf16_t* vS   = (bf16_t*)alloc(CH * 256 * 2);   // also num_s
    bf16_t* vH   = (bf16_t*)alloc(CH * 1920 * 2);  // also num_h
    bf16_t* TsK  = (bf16_t*)alloc(256L * CHP * 2);
    bf16_t* TsV  = (bf16_t*)alloc(256L * CHP * 2);
    bf16_t* ThK  = (bf16_t*)alloc(1920L * CHP * 2);
    bf16_t* ThV  = (bf16_t*)alloc(1920L * CHP * 2);
    float*  ktvS = (float*) alloc(8L * 32 * 32 * 4);
    float*  ktvH = (float*) alloc(8L * 240 * 256 * 4);
    bf16_t* ktvSb= (bf16_t*)alloc(8L * 32 * 32 * 2);
    bf16_t* ktvHb= (bf16_t*)alloc(8L * 240 * 256 * 2);
    float*  ksum_s = (float*)alloc(256L * 4);
    float*  ksum_h = (float*)alloc(1920L * 4);
    // query-phase f32 outputs carved from ThK (free after source phase)
    float* s_out = (float*)ThK;
    float* h_out = s_out + CH * SD;
    float* den_s = h_out + CH * HD;
    float* den_h = den_s + CH * H;

    // zero accumulators (ktvS..ksum_h are contiguous)
    {
        size_t span = (char*)(ksum_h + 1920) - (char*)ktvS;
        (void)hipMemsetAsync(ktvS, 0, span, stream);
    }

    // weight prep
    k_cast_pad<<<(unsigned)((2056L * KP + 255) / 256), 256, 0, stream>>>(Wq, Wqb, 2056, KIN, KP);
    k_cast_pad<<<(unsigned)((2056L * KP + 255) / 256), 256, 0, stream>>>(Wk, Wkb, 2056, KIN, KP);
    k_cast_pad<<<(unsigned)((2056L * KP + 255) / 256), 256, 0, stream>>>(Wv, Wvb, 2056, KIN, KP);
    k_cast_ws<<<17, 256, 0, stream>>>(Ws, Wsb);
    k_cast_pad<<<(unsigned)((240L * 1920 + 255) / 256), 256, 0, stream>>>(Wh, Whb, 240, 1920, 1920);

    const unsigned gM = (unsigned)((CH + BM - 1) / BM);
    GemmP g;

    // ---------------- source phase: build ktv + ksum ----------------
    for (int c = 0; c < NCHUNK; ++c) {
        const float* src = source + (long)c * CH * KIN;
        k_cast_pad<<<(unsigned)((CH * KP + 255) / 256), 256, 0, stream>>>(src, xcb, CH, KIN, KP);

        // Yk = xcb @ Wkb^T
        g = { xcb, KP, 0,  Wkb, KP, 0,  Y, 0, W2, 0,  0, 0, 0, 0.f,
              (int)CH, W2, KP, 1, 0 };
        k_mfma_nt<<<dim3(gM, (W2 + BN - 1) / BN, 1), 256, 0, stream>>>(g);
        k_post<<<(unsigned)((CH * H + 3) / 4), 256, 0, stream>>>(Y, phiS, phiH, (int)CH, 1);

        // Yv = xcb @ Wvb^T (reuse Y)
        g.B = Wvb;
        k_mfma_nt<<<dim3(gM, (W2 + BN - 1) / BN, 1), 256, 0, stream>>>(g);
        k_post<<<(unsigned)((CH * H + 3) / 4), 256, 0, stream>>>(Y, vS, vH, (int)CH, 0);

        // ksum accumulation (from bf16 phiK)
        k_colsum<<<dim3(1, 30), 256, 0, stream>>>(phiS, ksum_s, (int)CH, 256);
        k_colsum<<<dim3(8, 30), 256, 0, stream>>>(phiH, ksum_h, (int)CH, 1920);

        // transposes -> [cols][CHP]
        k_transpose<<<dim3((unsigned)(CHP / 128), 4),  256, 0, stream>>>(phiS, TsK, (int)CH, 256, (int)CHP);
        k_transpose<<<dim3((unsigned)(CHP / 128), 4),  256, 0, stream>>>(vS,   TsV, (int)CH, 256, (int)CHP);
        k_transpose<<<dim3((unsigned)(CHP / 128), 30), 256, 0, stream>>>(phiH, ThK, (int)CH, 1920, (int)CHP);
        k_transpose<<<dim3((unsigned)(CHP / 128), 30), 256, 0, stream>>>(vH,   ThV, (int)CH, 1920, (int)CHP);

        // ktvT_h[m(v),n(k')] += V^T phiK  : A=VhT, B=phiKhT, split-K atomic
        g = { ThV, CHP, 240 * CHP,  ThK, CHP, 240 * CHP,  ktvH, 0, 256, 240 * 256,
              0, 0, 0, 0.f,  240, 240, (int)CHP, 8, 1 };
        k_mfma_nt<<<dim3(2, 2, 64), 256, 0, stream>>>(g);
        g = { TsV, CHP, 32 * CHP,  TsK, CHP, 32 * CHP,  ktvS, 0, 32, 32 * 32,
              0, 0, 0, 0.f,  32, 32, (int)CHP, 8, 1 };
        k_mfma_nt<<<dim3(1, 1, 64), 256, 0, stream>>>(g);
    }
    k_castf<<<(unsigned)((8L * 240 * 256 + 255) / 256), 256, 0, stream>>>(ktvH, ktvHb, 8L * 240 * 256);
    k_castf<<<(unsigned)((8L * 32 * 32 + 255) / 256), 256, 0, stream>>>(ktvS, ktvSb, 8L * 32 * 32);

    // ---------------- query phase ----------------
    for (int c = 0; c < NCHUNK; ++c) {
        const float* qsrc = query + (long)c * CH * KIN;
        float* orow = out + (long)c * CH * OD;
        k_cast_pad<<<(unsigned)((CH * KP + 255) / 256), 256, 0, stream>>>(qsrc, xcb, CH, KIN, KP);

        // Yq = xcb @ Wqb^T
        g = { xcb, KP, 0,  Wqb, KP, 0,  Y, 0, W2, 0,  0, 0, 0, 0.f,
              (int)CH, W2, KP, 1, 0 };
        k_mfma_nt<<<dim3(gM, (W2 + BN - 1) / BN, 1), 256, 0, stream>>>(g);
        k_post_q<<<(unsigned)((CH * H + 3) / 4), 256, 0, stream>>>(
            Y, ksum_s, ksum_h, phiS, phiH, den_s, den_h, (int)CH);

        // num_h = (phiQh @ ktvT_h^T-as-NT) / den_h  -> bf16
        g = { phiH, 1920, 240,  ktvHb, 256, 240 * 256,  0, vH, 1920, 240,
              den_h, H, 1, 1e-8f,  (int)CH, 240, 240, 1, 0 };
        k_mfma_nt<<<dim3(gM, 2, 8), 256, 0, stream>>>(g);
        // num_s -> bf16
        g = { phiS, 256, 32,  ktvSb, 32, 32 * 32,  0, vS, 256, 32,
              den_s, H, 1, 1e-6f,  (int)CH, 32, 32, 1, 0 };
        k_mfma_nt<<<dim3(gM, 1, 8), 256, 0, stream>>>(g);

        // s_out = num_s @ Wsb^T  (f32)
        g = { vS, 256, 0,  Wsb, 256, 0,  s_out, 0, SD, 0,  0, 0, 0, 0.f,
              (int)CH, SD, 256, 1, 0 };
        k_mfma_nt<<<dim3(gM, 1, 1), 256, 0, stream>>>(g);
        // h_out = num_h @ Whb^T  (f32)
        g = { vH, 1920, 0,  Whb, 1920, 0,  h_out, 0, HD, 0,  0, 0, 0, 0.f,
              (int)CH, HD, 1920, 1, 0 };
        k_mfma_nt<<<dim3(gM, 2, 1), 256, 0, stream>>>(g);

        k_finalize<<<(unsigned)((CH + 3) / 4), 256, 0, stream>>>(s_out, h_out, orow, (int)CH);
    }
}